// Round 1
// baseline (868.409 us; speedup 1.0000x reference)
//
#include <hip/hip_runtime.h>

// AdaptiveEdgeSparsifier: per-row (n=4096) exact top-k threshold, keep >= kth
// largest (k=2867), zero the rest. One block per row; exact radix-256 select
// over order-preserving uint mapping; per-wave privatized LDS histograms.

#define NCOL 4096
#define KSEL 2867   // k = max(1, int(4096 * (1.0 - 0.3))) = 2867

__global__ __launch_bounds__(256) void sparsify_kernel(const float* __restrict__ adj,
                                                       float* __restrict__ out) {
    __shared__ unsigned hist[4][256];   // per-wave privatized histograms
    __shared__ unsigned s_state[2];     // [0] = prefix, [1] = remaining rank kr

    const int t    = threadIdx.x;
    const int wave = t >> 6;
    const int lane = t & 63;
    const size_t row = blockIdx.x;

    const float4* __restrict__ in4  = (const float4*)(adj + row * (size_t)NCOL);
    float4* __restrict__       out4 = (float4*)(out + row * (size_t)NCOL);

    // Load 16 elements per thread, coalesced float4 (16 B/lane).
    float4 v[4];
    unsigned u[16];
#pragma unroll
    for (int i = 0; i < 4; ++i) v[i] = in4[t + 256 * i];
#pragma unroll
    for (int i = 0; i < 4; ++i) {
        unsigned bx = __float_as_uint(v[i].x);
        unsigned by = __float_as_uint(v[i].y);
        unsigned bz = __float_as_uint(v[i].z);
        unsigned bw = __float_as_uint(v[i].w);
        // order-preserving map: positives -> [0x80000000,..], negatives -> ~bits
        u[4*i+0] = bx ^ ((unsigned)((int)bx >> 31) | 0x80000000u);
        u[4*i+1] = by ^ ((unsigned)((int)by >> 31) | 0x80000000u);
        u[4*i+2] = bz ^ ((unsigned)((int)bz >> 31) | 0x80000000u);
        u[4*i+3] = bw ^ ((unsigned)((int)bw >> 31) | 0x80000000u);
    }

    if (t == 0) { s_state[0] = 0u; s_state[1] = KSEL; }

    // 4 MSB-first radix-256 passes -> exact 32-bit value of kth largest.
#pragma unroll
    for (int p = 0; p < 4; ++p) {
        const int shift = 24 - 8 * p;
        const unsigned mask = (p == 0) ? 0u : (0xFFFFFFFFu << (32 - 8 * p));

        // zero all 4 histogram copies (256 threads x uint4 = 4 KiB)
        ((uint4*)hist)[t] = make_uint4(0u, 0u, 0u, 0u);
        __syncthreads();

        const unsigned pref = s_state[0];
        const unsigned kr   = s_state[1];

#pragma unroll
        for (int i = 0; i < 16; ++i) {
            if ((u[i] & mask) == pref)
                atomicAdd(&hist[wave][(u[i] >> shift) & 0xFFu], 1u);
        }
        __syncthreads();

        // Wave 0: reduce 4 copies, suffix-locate the bucket containing rank kr
        // (counting from the top / bucket 255 downward).
        if (wave == 0) {
            const uint4 a0 = *(const uint4*)&hist[0][4 * lane];
            const uint4 a1 = *(const uint4*)&hist[1][4 * lane];
            const uint4 a2 = *(const uint4*)&hist[2][4 * lane];
            const uint4 a3 = *(const uint4*)&hist[3][4 * lane];
            unsigned cc[4];
            cc[0] = a0.x + a1.x + a2.x + a3.x;
            cc[1] = a0.y + a1.y + a2.y + a3.y;
            cc[2] = a0.z + a1.z + a2.z + a3.z;
            cc[3] = a0.w + a1.w + a2.w + a3.w;
            unsigned s = cc[0] + cc[1] + cc[2] + cc[3];

            // inclusive prefix sum over lanes
            unsigned pscan = s;
#pragma unroll
            for (int d = 1; d < 64; d <<= 1) {
                unsigned nv = __shfl_up(pscan, d, 64);
                if (lane >= d) pscan += nv;
            }
            const unsigned total = __shfl(pscan, 63, 64);
            unsigned cum = total - pscan;  // count in buckets above lane's top slot

            // walk this lane's 4 buckets from high (slot 3) to low (slot 0)
#pragma unroll
            for (int s2 = 3; s2 >= 0; --s2) {
                const unsigned nxt = cum + cc[s2];
                if (cum < kr && kr <= nxt) {   // exactly one (lane,slot) hits
                    s_state[0] = pref | ((unsigned)(4 * lane + s2) << shift);
                    s_state[1] = kr - cum;
                }
                cum = nxt;
            }
        }
        __syncthreads();
    }

    // Exact threshold; inverse of the order-preserving map.
    const unsigned tu = s_state[0];
    const unsigned tb = (tu & 0x80000000u) ? (tu ^ 0x80000000u) : ~tu;
    const float thr = __uint_as_float(tb);

#pragma unroll
    for (int i = 0; i < 4; ++i) {
        float4 o;
        o.x = (v[i].x >= thr) ? v[i].x : 0.0f;
        o.y = (v[i].y >= thr) ? v[i].y : 0.0f;
        o.z = (v[i].z >= thr) ? v[i].z : 0.0f;
        o.w = (v[i].w >= thr) ? v[i].w : 0.0f;
        out4[t + 256 * i] = o;
    }
}

extern "C" void kernel_launch(void* const* d_in, const int* in_sizes, int n_in,
                              void* d_out, int out_size, void* d_ws, size_t ws_size,
                              hipStream_t stream) {
    const float* adj = (const float*)d_in[0];
    float* out = (float*)d_out;
    const int rows = in_sizes[0] / NCOL;  // 8 * 4096 = 32768
    sparsify_kernel<<<rows, 256, 0, stream>>>(adj, out);
}